// Round 13
// baseline (124.517 us; speedup 1.0000x reference)
//
#include <hip/hip_runtime.h>
#include <hip/hip_bf16.h>
#include <cstdint>

// CrossAttentionMultiHead: B=8, C=512, H=W=64 (S=4096), L=77, E=768, heads=4 (dh=128), GN groups=8.
// FP32 I/O; attention_mask int32. Compute in bf16 MFMA, fp32 accum.
// R8: KWq fold — scores S[s][l] = x[s][:]·KWq[l][:] + kb[l], KWq_h = K·Wq_h (k1b).
// R13: XCD-aware k2 grid (bz fastest) -> XCD = bz. R14: tiled xT [bz][cc=8][s][64c].
// R15: k_fat KV register-prefetch dbuf. R16: bf16 outTmp epilogue + k3_gn_b.
// R18: A-resident score loop (zero in-loop barriers) — but [80][512] LDS layout had 1024B row
//      stride == bank 0 -> SQ_LDS_BANK_CONFLICT 393K -> 1.7M, eating the barrier win.
// R19: repair the confound — A stored CHUNK-TILED arena[kc][80][64] (row stride 128B, the
//      R9/R17-proven conflict-free pattern). Linear global_load_lds dest IS this layout
//      (u = kc*640 + l*8 + sg; 640 = 10 waves -> wave-instrs never straddle chunks); source
//      pre-swizzled sg^(l&7). Score loop still ZERO barriers. Single variable vs R18.

typedef __attribute__((ext_vector_type(8))) short short8;
typedef __attribute__((ext_vector_type(4))) short short4v;
typedef __attribute__((ext_vector_type(4))) float f32x4;

#define DEV __device__ __forceinline__

DEV float bf2f(unsigned short u){ union{uint32_t i; float f;} x; x.i = ((uint32_t)u) << 16; return x.f; }
DEV unsigned short f2bf(float f){ __hip_bfloat16 h = __float2bfloat16(f); return *reinterpret_cast<unsigned short*>(&h); }
DEV short8 ld8(const unsigned short* p){ return *reinterpret_cast<const short8*>(p); }
DEV f32x4 ldf4(const float* p){ return *reinterpret_cast<const f32x4*>(p); }

#if defined(__has_builtin)
#if __has_builtin(__builtin_amdgcn_global_load_lds)
#define HAVE_ASYNC_LDS 1
#endif
#endif

// ---------------------------------------------------------------- fat kernel
// bx in {0,1}: K/V projection (uc = bx*8+by). bx == 2: Wq fp32 -> WqT[c][d] bf16.
// bx >= 3: x transpose tile (bx-3) -> tiled xTt.
__global__ __launch_bounds__(256) void k_fat(const float* __restrict__ x,
                                             unsigned short* __restrict__ xTt,
                                             const float* __restrict__ text,
                                             const float* __restrict__ Wk,
                                             const float* __restrict__ Wkb,
                                             const float* __restrict__ Wv,
                                             const float* __restrict__ Wvb,
                                             unsigned short* __restrict__ wsK,
                                             unsigned short* __restrict__ wsVt,
                                             const float* __restrict__ Wq,
                                             unsigned short* __restrict__ wsWqT,
                                             int b0, int s_base, int slen, int SB){
  __shared__ unsigned short U[16896];            // 64 x 264 (transpose) / KV arena / Wq tile
  const int tid = threadIdx.x;
  const int bx = blockIdx.x, by = blockIdx.y, bz = blockIdx.z;
  const int bg = b0 + bz;

  if (bx >= 3){
    // ---------------- transpose x[b][c0+r][s0..s0+256) fp32 -> xTt[bz][cc][sloc][r] bf16
    const int cc = by, c0 = cc * 64;
    const int tile = bx - 3;
    const int s0 = s_base + tile * 256;
    {
      const int r = tid >> 2, sub = tid & 3;     // 4 threads per c-row, 256B each
      const float* src = &x[((size_t)(bg * 512 + c0 + r)) * 4096 + s0 + sub * 64];
      f32x4 rv[16];
      #pragma unroll
      for (int i = 0; i < 16; ++i) rv[i] = ldf4(src + i * 4);   // all 16 loads in flight
      unsigned short* drow = &U[r * 264 + sub * 64];
      #pragma unroll
      for (int i = 0; i < 8; ++i){
        short8 v;
        #pragma unroll
        for (int j = 0; j < 4; ++j){ v[j] = (short)f2bf(rv[2*i][j]); v[j + 4] = (short)f2bf(rv[2*i+1][j]); }
        *reinterpret_cast<short8*>(drow + i * 8) = v;
      }
    }
    __syncthreads();
    {
      const int j = tid;                         // output s-row (local 0..255)
      unsigned short v[64];
      #pragma unroll
      for (int r = 0; r < 64; ++r) v[r] = U[r * 264 + j];   // column gather, 2-way banks (free)
      const int sloc = tile * 256 + j;
      unsigned short* dst = &xTt[(((size_t)bz * 8 + cc) * slen + sloc) * 64];
      #pragma unroll
      for (int g = 0; g < 8; ++g)
        *reinterpret_cast<short8*>(dst + g * 8) = *reinterpret_cast<short8*>(&v[g * 8]);
    }
  } else if (bx < 2){
    // ---------------- K/V projection: out[80l x 64u] = text[80x768] @ W[u]^T, BK=64
    // Register-prefetch dbuf: chunk k+1's 9 f32x4 loads issued before compute(k).
    unsigned short* At = U;                      // 80 x 72
    unsigned short* Bt = U + 5760;               // 64 x 72
    const int wave = tid >> 6, lane = tid & 63;
    const int m16 = lane & 15, quad = lane >> 4;
    const int uc = bx * 8 + by;
    const int u0 = uc * 64;
    const bool isK = (u0 < 512);
    const float* W  = isK ? Wk  : Wv;
    const float* Wb = isK ? Wkb : Wvb;
    const int c0 = u0 & 511;
    const int c  = c0 + wave * 16 + m16;         // this lane's output column

    int srow[9], se4[9]; bool sA[9], sval[9];
    #pragma unroll
    for (int it = 0; it < 9; ++it){
      int slot = tid + it * 256;
      if (slot < 1280){ sA[it] = true;  srow[it] = slot >> 4;          se4[it] = (slot & 15) * 4; sval[it] = (srow[it] < 77); }
      else            { sA[it] = false; srow[it] = (slot - 1280) >> 4; se4[it] = ((slot - 1280) & 15) * 4; sval[it] = true; }
    }
    f32x4 preg[9];
    auto issue = [&](int kc){
      const int e0 = kc * 64;
      #pragma unroll
      for (int it = 0; it < 9; ++it){
        if (sA[it])
          preg[it] = sval[it] ? ldf4(&text[((size_t)(bg * 77 + srow[it])) * 768 + e0 + se4[it]])
                              : (f32x4){0.f, 0.f, 0.f, 0.f};
        else
          preg[it] = ldf4(&W[((size_t)(c0 + srow[it])) * 768 + e0 + se4[it]]);
      }
    };
    auto write_lds = [&](){
      #pragma unroll
      for (int it = 0; it < 9; ++it){
        short4v o;
        #pragma unroll
        for (int j = 0; j < 4; ++j) o[j] = (short)f2bf(preg[it][j]);
        if (sA[it]) *reinterpret_cast<short4v*>(&At[srow[it] * 72 + se4[it]]) = o;
        else        *reinterpret_cast<short4v*>(&Bt[srow[it] * 72 + se4[it]]) = o;
      }
    };

    f32x4 acc[5];
    #pragma unroll
    for (int mt = 0; mt < 5; ++mt) acc[mt] = (f32x4){0.f, 0.f, 0.f, 0.f};
    issue(0);
    for (int kc = 0; kc < 12; ++kc){
      write_lds();                               // waits on prefetched loads
      __syncthreads();                           // LDS tile ready
      if (kc < 11) issue(kc + 1);                // next chunk's loads fly during compute
      #pragma unroll
      for (int kk = 0; kk < 64; kk += 32){
        short8 bf_ = *reinterpret_cast<const short8*>(&Bt[(wave * 16 + m16) * 72 + kk + quad * 8]);
        #pragma unroll
        for (int mt = 0; mt < 5; ++mt){
          short8 af_ = *reinterpret_cast<const short8*>(&At[(mt * 16 + m16) * 72 + kk + quad * 8]);
          acc[mt] = __builtin_amdgcn_mfma_f32_16x16x32_bf16(af_, bf_, acc[mt], 0, 0, 0);
        }
      }
      __syncthreads();                           // compute done before next overwrite
    }
    const float bias = Wb[c];
    if (isK){
      #pragma unroll
      for (int mt = 0; mt < 5; ++mt)
        #pragma unroll
        for (int r = 0; r < 4; ++r){
          int l = mt * 16 + quad * 4 + r;
          if (l < 77) wsK[((size_t)(bz * 77 + l)) * 512 + c] = f2bf(acc[mt][r] + bias);
        }
    } else {
      unsigned short* vr = &wsVt[((size_t)(bz * 512 + c)) * 96];
      #pragma unroll
      for (int mt = 0; mt < 5; ++mt){
        short4v pk;
        #pragma unroll
        for (int r = 0; r < 4; ++r) pk[r] = (short)f2bf(acc[mt][r] + bias);
        *reinterpret_cast<short4v*>(&vr[mt * 16 + quad * 4]) = pk;
      }
      short4v z = {};
      *reinterpret_cast<short4v*>(&vr[80 + quad * 4]) = z;   // zero l=80..95
    }
  } else {
    // ---------------- Wq[512 d][512 c] fp32 -> wsWqT[c][d] bf16 (64 tiles of 64x64, LDS transpose)
    unsigned short* t = U;                       // 64x72
    const int nb = 8 * SB;
    const int p  = by + bz * 8;
    for (int tile = p; tile < 64; tile += nb){
      const int ti = tile >> 3, tj = tile & 7;   // ti: c-tile, tj: d-tile
      {
        const int r = tid >> 2, sub = tid & 3;   // 4 threads per d-row, 16 c each
        const float* src = &Wq[((size_t)(tj * 64 + r)) * 512 + ti * 64 + sub * 16];
        f32x4 rv[4];
        #pragma unroll
        for (int i = 0; i < 4; ++i) rv[i] = ldf4(src + i * 4);
        unsigned short* drow = &t[r * 72 + sub * 16];
        #pragma unroll
        for (int i = 0; i < 2; ++i){
          short8 v;
          #pragma unroll
          for (int j = 0; j < 4; ++j){ v[j] = (short)f2bf(rv[2*i][j]); v[j + 4] = (short)f2bf(rv[2*i+1][j]); }
          *reinterpret_cast<short8*>(drow + i * 8) = v;
        }
      }
      __syncthreads();
      #pragma unroll
      for (int it = 0; it < 2; ++it){
        int slot = tid + it * 256;
        int j = slot >> 3, i8 = slot & 7;        // j: c-row out, i8: d-group
        short8 v;
        #pragma unroll
        for (int q = 0; q < 8; ++q)
          v[q] = (short)t[(i8 * 8 + q) * 72 + (j & 63)];
        *reinterpret_cast<short8*>(&wsWqT[((size_t)(ti * 64 + j)) * 512 + tj * 64 + i8 * 8]) = v;
      }
      __syncthreads();
    }
  }
}

// ---------------------------------------------------------------- k1b: KWq[l][c] = K_h[l][:] @ Wq_h[:][c],
// plus kb[l] = K_h[l][:]·Wqb_h. grid (cq=4, h=4, bz=SB). All operands bf16, direct from global (L2-hot).
__global__ __launch_bounds__(256) void k1b(const unsigned short* __restrict__ wsWqT,
                                           const unsigned short* __restrict__ wsK,
                                           const float* __restrict__ Wqb,
                                           unsigned short* __restrict__ wsKWq,
                                           float* __restrict__ kbias){
  const int tid = threadIdx.x;
  const int wave = tid >> 6, lane = tid & 63;
  const int m16 = lane & 15, quad = lane >> 4;
  const int cq = blockIdx.x, h = blockIdx.y, bz = blockIdx.z;
  const int cbase = cq * 128 + wave * 32;

  f32x4 acc[2][5];
  #pragma unroll
  for (int mt = 0; mt < 2; ++mt)
    #pragma unroll
    for (int nt = 0; nt < 5; ++nt) acc[mt][nt] = (f32x4){0.f, 0.f, 0.f, 0.f};

  #pragma unroll
  for (int ks = 0; ks < 4; ++ks){
    short8 aw[2];
    #pragma unroll
    for (int mt = 0; mt < 2; ++mt)
      aw[mt] = ld8(&wsWqT[(size_t)(cbase + mt * 16 + m16) * 512 + h * 128 + ks * 32 + quad * 8]);
    #pragma unroll
    for (int nt = 0; nt < 5; ++nt){
      int l = nt * 16 + m16;
      short8 bk = {};
      if (l < 77) bk = ld8(&wsK[((size_t)(bz * 77 + l)) * 512 + h * 128 + ks * 32 + quad * 8]);
      #pragma unroll
      for (int mt = 0; mt < 2; ++mt)
        acc[mt][nt] = __builtin_amdgcn_mfma_f32_16x16x32_bf16(aw[mt], bk, acc[mt][nt], 0, 0, 0);
    }
  }
  #pragma unroll
  for (int mt = 0; mt < 2; ++mt)
    #pragma unroll
    for (int nt = 0; nt < 5; ++nt){
      int l = nt * 16 + m16;
      short4v pk;
      #pragma unroll
      for (int r = 0; r < 4; ++r) pk[r] = (short)f2bf(acc[mt][nt][r]);
      *reinterpret_cast<short4v*>(&wsKWq[((size_t)((bz * 4 + h) * 80 + l)) * 512 + cbase + mt * 16 + quad * 4]) = pk;
    }
  if (cq == 0 && tid < 80){
    int l = tid;
    float kb = 0.f;
    if (l < 77){
      #pragma unroll
      for (int d = 0; d < 128; d += 8){
        short8 kv = ld8(&wsK[((size_t)(bz * 77 + l)) * 512 + h * 128 + d]);
        f32x4 wa = ldf4(&Wqb[h * 128 + d]);
        f32x4 wb = ldf4(&Wqb[h * 128 + d + 4]);
        #pragma unroll
        for (int j = 0; j < 4; ++j){
          kb += bf2f((unsigned short)kv[j]) * wa[j];
          kb += bf2f((unsigned short)kv[j + 4]) * wb[j];
        }
      }
    }
    kbias[(bz * 4 + h) * 80 + l] = kb;
  }
}

// ---------------------------------------------------------------- k2: scores + softmax + PV + GN partials
// Grid (bz, h, st), XCD = bz. A (KWq_h) resident in LDS, CHUNK-TILED arena[kc][80][64]
// (row stride 128B, conflict-free). Staged ONCE; score loop has ZERO barriers —
// B in two depth-4 register batches. Pt[128][104]/T[32][132] alias arena after the loop.
__global__ __launch_bounds__(256, 2) void k2_attn(const unsigned short* __restrict__ xTt,
                                                  const unsigned short* __restrict__ wsKWq,
                                                  const unsigned short* __restrict__ wsVt,
                                                  const int* __restrict__ amask,
                                                  const float* __restrict__ kbias,
                                                  float* __restrict__ out,
                                                  unsigned short* __restrict__ outTmp,
                                                  float* __restrict__ gnacc,
                                                  int b0, int s_base, int slen, int useTmp){
  __shared__ unsigned short arena[40960];        // 8 x [80][64] = 80KB; Pt/T alias after score loop
  unsigned short* Pt = arena;                    // [128][104]

  const int tid = threadIdx.x;
  const int wave = tid >> 6, lane = tid & 63;
  const int m16 = lane & 15, quad = lane >> 4;
  const int bz = blockIdx.x, h = blockIdx.y, st = blockIdx.z;   // XCD = bz
  const int bg = b0 + bz;
  const int s_glob = s_base + st * 128;
  const int R0 = (wave >> 1) * 64, C0 = (wave & 1) * 64;   // PV decomposition
  const int sw0 = wave * 32;                               // score-phase s-range of this wave
  const float scale = 0.08838834764831845f;                // 1/sqrt(128)

  const unsigned short* Abase = wsKWq + (size_t)((bz * 4 + h) * 80) * 512;
  const unsigned short* Bb    = xTt + (size_t)(bz * 8) * slen * 64;   // tiled batch base
  const int srow0 = st * 128 + sw0;                                   // wave's s-row base

  // ---- stage the WHOLE A tile once, chunk-tiled: u = kc*640 + l*8 + sg (640 = 10 waves,
  // so each wave-instr stays in one chunk). Linear LDS dest u*16B == arena[kc][l][sg*8].
  // Source col-group pre-swizzled sg^(l&7) -> score-loop ds_read_b128 is the R9-proven pattern.
  #pragma unroll
  for (int i = 0; i < 20; ++i){
    const int ubase = i * 256 + wave * 64;
    const int u = ubase + lane;
    const int kc = u / 640, uu = u - kc * 640;
    const int l = uu >> 3, sg = uu & 7;
    const unsigned short* src = Abase + (size_t)l * 512 + kc * 64 + (sg ^ (l & 7)) * 8;
#ifdef HAVE_ASYNC_LDS
    __builtin_amdgcn_global_load_lds((const __attribute__((address_space(1))) void*)src,
                                     (__attribute__((address_space(3))) void*)&arena[ubase * 8],
                                     16, 0, 0);
#else
    *reinterpret_cast<short8*>(&arena[u * 8]) = ld8(src);
#endif
  }

  // ---- B fragments: chunks in two depth-4 register batches (16 short8 = 64 VGPR)
  short8 Breg[4][4];                             // [chunk-in-batch][nt*2+kk]
  auto loadB = [&](int kc, int slot){
    const unsigned short* Bc = Bb + ((size_t)kc * slen + srow0) * 64;
    #pragma unroll
    for (int nt = 0; nt < 2; ++nt)
      #pragma unroll
      for (int kk = 0; kk < 2; ++kk)
        Breg[slot][nt * 2 + kk] = ld8(&Bc[(size_t)(nt * 16 + m16) * 64 + kk * 32 + quad * 8]);
  };
  #pragma unroll
  for (int c4 = 0; c4 < 4; ++c4) loadB(c4, c4);  // batch 0 in flight during A-stage drain

  // ---- per-thread mask+bias values (no LDS; loads hide under staging)
  float mb[5][4];
  #pragma unroll
  for (int mt = 0; mt < 5; ++mt)
    #pragma unroll
    for (int r = 0; r < 4; ++r){
      int l = mt * 16 + quad * 4 + r;
      float v = -30000.f;
      if (l < 77 && amask[bg * 77 + l] != 0) v = kbias[(bz * 4 + h) * 80 + l] * scale;
      mb[mt][r] = v;
    }

  f32x4 acc2[5][2];
  #pragma unroll
  for (int mt = 0; mt < 5; ++mt){ acc2[mt][0] = (f32x4){0.f,0.f,0.f,0.f}; acc2[mt][1] = (f32x4){0.f,0.f,0.f,0.f}; }

  auto compute = [&](int kc, int slot){
    const int ab = kc * 5120;                    // chunk base (shorts)
    #pragma unroll
    for (int kk = 0; kk < 2; ++kk){
      short8 af[5];
      #pragma unroll
      for (int mt = 0; mt < 5; ++mt){
        int l = mt * 16 + m16;
        int p = (kk * 4 + quad) ^ (l & 7);
        af[mt] = *reinterpret_cast<const short8*>(&arena[ab + l * 64 + p * 8]);
      }
      #pragma unroll
      for (int mt = 0; mt < 5; ++mt)
        #pragma unroll
        for (int nt = 0; nt < 2; ++nt)
          acc2[mt][nt] = __builtin_amdgcn_mfma_f32_16x16x32_bf16(af[mt], Breg[slot][nt * 2 + kk], acc2[mt][nt], 0, 0, 0);
    }
  };

  __syncthreads();                               // A tile fully staged (single drain)

  // ---- score loop: NO barriers
  #pragma unroll
  for (int kc = 0; kc < 4; ++kc) compute(kc, kc);
  #pragma unroll
  for (int kc = 4; kc < 8; ++kc) loadB(kc, kc - 4);
  #pragma unroll
  for (int kc = 4; kc < 8; ++kc) compute(kc, kc - 4);

  // ---- prefetch PV's ks=0 V fragments; latency hides under softmax
  const unsigned short* Vb = wsVt + (size_t)(bz * 512 + h * 128) * 96;
  short8 av0[4];
  #pragma unroll
  for (int mt = 0; mt < 4; ++mt)
    av0[mt] = ld8(&Vb[(size_t)(R0 + mt * 16 + m16) * 96 + quad * 8]);

  __syncthreads();                               // all waves done READING A; arena reusable

  // ---- softmax over l (per s-column), Pt -> arena [s][l] stride 104
  #pragma unroll
  for (int nt = 0; nt < 2; ++nt){
    float sv[5][4]; float mx = -3e38f;
    #pragma unroll
    for (int mt = 0; mt < 5; ++mt)
      #pragma unroll
      for (int r = 0; r < 4; ++r){
        float v = acc2[mt][nt][r] * scale + mb[mt][r];
        sv[mt][r] = v; mx = fmaxf(mx, v);
      }
    mx = fmaxf(mx, __shfl_xor(mx, 16)); mx = fmaxf(mx, __shfl_xor(mx, 32));
    float sum = 0.f;
    #pragma unroll
    for (int mt = 0; mt < 5; ++mt)
      #pragma unroll
      for (int r = 0; r < 4; ++r){ float e = __expf(sv[mt][r] - mx); sv[mt][r] = e; sum += e; }
    sum += __shfl_xor(sum, 16); sum += __shfl_xor(sum, 32);
    float inv = 1.0f / sum;
    int sl = sw0 + nt * 16 + m16;
    #pragma unroll
    for (int mt = 0; mt < 5; ++mt){
      short4v pk;
      #pragma unroll
      for (int r = 0; r < 4; ++r) pk[r] = (short)f2bf(sv[mt][r] * inv);
      *reinterpret_cast<short4v*>(&Pt[sl * 104 + mt * 16 + quad * 4]) = pk;
    }
    short4v z = {};
    *reinterpret_cast<short4v*>(&Pt[sl * 104 + 80 + quad * 4]) = z;  // zero l=80..95
  }
  __syncthreads();                               // Pt ready for cross-wave reads

  // ---- PV: Ot = Vt[128x96] @ Pt[96 x 128s]; Vt fragments direct from global
  f32x4 acc3[4][4];
  #pragma unroll
  for (int mt = 0; mt < 4; ++mt)
    #pragma unroll
    for (int nt = 0; nt < 4; ++nt) acc3[mt][nt] = (f32x4){0.f, 0.f, 0.f, 0.f};
  #pragma unroll
  for (int ks = 0; ks < 3; ++ks){
    short8 av[4], bp[4];
    #pragma unroll
    for (int mt = 0; mt < 4; ++mt)
      av[mt] = (ks == 0) ? av0[mt]
                         : ld8(&Vb[(size_t)(R0 + mt * 16 + m16) * 96 + ks * 32 + quad * 8]);
    #pragma unroll
    for (int nt = 0; nt < 4; ++nt)
      bp[nt] = *reinterpret_cast<const short8*>(&Pt[(C0 + nt * 16 + m16) * 104 + ks * 32 + quad * 8]);
    #pragma unroll
    for (int mt = 0; mt < 4; ++mt)
      #pragma unroll
      for (int nt = 0; nt < 4; ++nt)
        acc3[mt][nt] = __builtin_amdgcn_mfma_f32_16x16x32_bf16(av[mt], bp[nt], acc3[mt][nt], 0, 0, 0);
  }

  // ---- GN partials from fp32 accumulators
  float sum = 0.f, ssq = 0.f;
  #pragma unroll
  for (int mt = 0; mt < 4; ++mt)
    #pragma unroll
    for (int nt = 0; nt < 4; ++nt)
      #pragma unroll
      for (int r = 0; r < 4; ++r){
        float v = acc3[mt][nt][r];
        sum += v; ssq += v * v;
      }
  #pragma unroll
  for (int off = 1; off < 64; off <<= 1){ sum += __shfl_xor(sum, off); ssq += __shfl_xor(ssq, off); }
  if (lane == 0){
    int g = h * 2 + (R0 >> 6);
    atomicAdd(&gnacc[(bg * 8 + g) * 2],     sum);
    atomicAdd(&gnacc[(bg * 8 + g) * 2 + 1], ssq);
  }

  if (useTmp){
    // ---- epilogue A: LDS transpose -> BF16 256B-contiguous rows outTmp[c][s_glob..+127]
    __syncthreads();                              // all Pt reads done; arena reused as T
    float* T = reinterpret_cast<float*>(arena);   // [32][132]
    const int TS = 132;
    #pragma unroll
    for (int p = 0; p < 4; ++p){
      if ((R0 >> 6) == (p >> 1)){
        #pragma unroll
        for (int mt2 = 0; mt2 < 2; ++mt2){
          int mt = (p & 1) * 2 + mt2;
          #pragma unroll
          for (int nt = 0; nt < 4; ++nt)
            #pragma unroll
            for (int r = 0; r < 4; ++r)
              T[(mt2 * 16 + quad * 4 + r) * TS + C0 + nt * 16 + m16] = acc3[mt][nt][r];
        }
      }
      __syncthreads();
      #pragma unroll
      for (int it = 0; it < 4; ++it){
        int row = wave * 8 + it * 2 + (lane >> 5);  // 0..31
        int c = h * 128 + p * 32 + row;
        int sc = (lane & 31) * 4;
        f32x4 v = *reinterpret_cast<const f32x4*>(&T[row * TS + sc]);
        short4v o;
        #pragma unroll
        for (int j = 0; j < 4; ++j) o[j] = (short)f2bf(v[j]);
        *reinterpret_cast<short4v*>(&outTmp[(size_t)(bg * 512 + c) * 4096 + s_glob + sc]) = o;
      }
      __syncthreads();
    }
  } else {
    // ---- epilogue B (fallback): scattered fp32 stores to out
    #pragma unroll
    for (int mt = 0; mt < 4; ++mt)
      #pragma unroll
      for (int nt = 0; nt < 4; ++nt){
        int sidx = s_glob + C0 + nt * 16 + m16;
        #pragma unroll
        for (int r = 0; r < 4; ++r){
          int d = h * 128 + R0 + mt * 16 + quad * 4 + r;
          out[(size_t)(bg * 512 + d) * 4096 + sidx] = acc3[mt][nt][r];
        }
      }
  }
}

// ---------------------------------------------------------------- k3a: GN apply from bf16 tmp -> fp32 out
__global__ __launch_bounds__(256) void k3_gn_b(const unsigned short* __restrict__ tmp,
                                               float* __restrict__ out,
                                               const float* __restrict__ gnacc,
                                               const float* __restrict__ gns,
                                               const float* __restrict__ gnb){
  const int bx = blockIdx.x;                 // bx = b*512 + c
  const int b = bx >> 9, c = bx & 511;
  const int g = c >> 6;
  const float s  = gnacc[(b * 8 + g) * 2];
  const float ss = gnacc[(b * 8 + g) * 2 + 1];
  const float invN = 1.f / 262144.f;
  const float mean = s * invN;
  const float var  = ss * invN - mean * mean;
  const float rstd = rsqrtf(fmaxf(var, 0.f) + 1e-5f);
  const float a  = rstd * gns[c];
  const float bb = gnb[c] - mean * a;
  const size_t base = (size_t)bx * 4096;
  const unsigned short* src = &tmp[base + threadIdx.x * 16];
  float* dst = &out[base + threadIdx.x * 16];
  short8 v0 = ld8(src), v1 = ld8(src + 8);
  #pragma unroll
  for (int k = 0; k < 2; ++k){
    short8 v = k ? v1 : v0;
    f32x4 o0, o1;
    #pragma unroll
    for (int j = 0; j < 4; ++j){
      o0[j] = bf2f((unsigned short)v[j])     * a + bb;
      o1[j] = bf2f((unsigned short)v[j + 4]) * a + bb;
    }
    *reinterpret_cast<f32x4*>(dst + k * 8)     = o0;
    *reinterpret_cast<f32x4*>(dst + k * 8 + 4) = o1;
  }
}

// ---------------------------------------------------------------- k3b: GN apply in-place fp32 (fallback)
__global__ __launch_bounds__(256) void k3_gn(float* __restrict__ out,
                                             const float* __restrict__ gnacc,
                                             const float* __restrict__ gns,
                                             const float* __restrict__ gnb){
  const int bx = blockIdx.x;                 // bx = b*512 + c
  const int b = bx >> 9, c = bx & 511;
  const int g = c >> 6;
  const float s  = gnacc[(b * 8 + g) * 2];
  const float ss = gnacc[(b * 8 + g) * 2 + 1];
  const float invN = 1.f / 262144.f;
  const float mean = s * invN;
  const float var  = ss * invN - mean * mean;
  const float rstd = rsqrtf(fmaxf(var, 0.f) + 1e-5f);
  const float a  = rstd * gns[c];
  const float bb = gnb[c] - mean * a;
  const size_t base = (size_t)bx * 4096;
  #pragma unroll
  for (int p = 0; p < 4; ++p){
    size_t off = base + p * 1024 + threadIdx.x * 4;
    f32x4 v = ldf4(&out[off]);
    f32x4 o;
    #pragma unroll
    for (int j = 0; j < 4; ++j) o[j] = v[j] * a + bb;
    *reinterpret_cast<f32x4*>(&out[off]) = o;
  }
}

// ---------------------------------------------------------------- launch
extern "C" void kernel_launch(void* const* d_in, const int* in_sizes, int n_in,
                              void* d_out, int out_size, void* d_ws, size_t ws_size,
                              hipStream_t stream){
  (void)in_sizes; (void)n_in; (void)out_size;
  const float* x    = (const float*)d_in[0];
  const float* text = (const float*)d_in[1];
  const int*   am   = (const int*)d_in[2];
  const float* Wq   = (const float*)d_in[3];
  const float* Wqb  = (const float*)d_in[4];
  const float* Wk   = (const float*)d_in[5];
  const float* Wkb  = (const float*)d_in[6];
  const float* Wv   = (const float*)d_in[7];
  const float* Wvb  = (const float*)d_in[8];
  const float* gns  = (const float*)d_in[9];
  const float* gnb  = (const float*)d_in[10];
  float* out = (float*)d_out;

  // ws: gnacc 512 + wsWqT 512KB + SB*(wsK + wsVt + wsKWq + kbias) + SB*SLEN*1024 (xTt) [+ 32MB outTmp]
  auto need = [](int SB, int SLEN) -> size_t {
    return 512ull + 524288ull + (size_t)SB * 506112ull + (size_t)SB * SLEN * 1024ull;
  };
  int SB = 8, SLEN = 4096;
  if      (ws_size >= need(8, 4096)) { SB = 8; SLEN = 4096; }
  else if (ws_size >= need(4, 4096)) { SB = 4; SLEN = 4096; }
  else if (ws_size >= need(2, 4096)) { SB = 2; SLEN = 4096; }
  else if (ws_size >= need(1, 4096)) { SB = 1; SLEN = 4096; }
  else if (ws_size >= need(1, 1024)) { SB = 1; SLEN = 1024; }
  else                               { SB = 1; SLEN = 256;  }

  const size_t tmpBytes = 8ull * 512 * 4096 * 2;   // 32 MB bf16 intermediate
  const int useTmp = (SB == 8 && SLEN == 4096 && ws_size >= need(8, 4096) + tmpBytes) ? 1 : 0;

  uint8_t* ws = (uint8_t*)d_ws;
  float*          gnacc = (float*)ws;
  unsigned short* wsWqT = (unsigned short*)(ws + 512);                  // [512 c][512 d] bf16
  unsigned short* wsK   = wsWqT + 512 * 512;                            // [SB][77][512]
  unsigned short* wsVt  = wsK  + (size_t)SB * 77 * 512;                 // [SB][512][96]
  unsigned short* wsKWq = wsVt + (size_t)SB * 512 * 96;                 // [SB*4][80][512]
  float*          kbias = (float*)(wsKWq + (size_t)SB * 4 * 80 * 512);  // [SB*4][80]
  unsigned short* xTt   = (unsigned short*)(kbias + (size_t)SB * 4 * 80); // [SB][8cc][SLEN][64]
  unsigned short* outTmp = xTt + (size_t)SB * 8 * SLEN * 64;            // [8][512][4096] bf16

  hipMemsetAsync(gnacc, 0, 128 * sizeof(float), stream);
  for (int b0 = 0; b0 < 8; b0 += SB){
    for (int s_base = 0; s_base < 4096; s_base += SLEN){
      const int NT = SLEN >> 8;
      k_fat<<<dim3(NT + 3, 8, SB), 256, 0, stream>>>(x, xTt, text, Wk, Wkb, Wv, Wvb,
                                                     wsK, wsVt, Wq, wsWqT, b0, s_base, SLEN, SB);
      if (s_base == 0)
        k1b<<<dim3(4, 4, SB), 256, 0, stream>>>(wsWqT, wsK, Wqb, wsKWq, kbias);
      // XCD-aware grid (bz fastest, h, st)
      k2_attn<<<dim3(SB, 4, SLEN / 128), 256, 0, stream>>>(xTt, wsKWq, wsVt, am, kbias,
                                                           out, outTmp, gnacc,
                                                           b0, s_base, SLEN, useTmp);
    }
  }
  if (useTmp)
    k3_gn_b<<<4096, 256, 0, stream>>>(outTmp, out, gnacc, gns, gnb);
  else
    k3_gn<<<4096, 256, 0, stream>>>(out, gnacc, gns, gnb);
}

// Round 14
// 117.839 us; speedup vs baseline: 1.0567x; 1.0567x over previous
//
#include <hip/hip_runtime.h>
#include <hip/hip_bf16.h>
#include <cstdint>

// CrossAttentionMultiHead: B=8, C=512, H=W=64 (S=4096), L=77, E=768, heads=4 (dh=128), GN groups=8.
// FP32 I/O; attention_mask int32. Compute in bf16 MFMA, fp32 accum.
// R8: KWq fold — scores S[s][l] = x[s][:]·KWq[l][:] + kb[l], KWq_h = K·Wq_h (k1b).
// R13: XCD-aware k2 grid (bz fastest) -> XCD = bz. R14: tiled xT [bz][cc=8][s][64c].
// R15: k_fat KV register-prefetch dbuf (132->118us). R16: bf16 outTmp epilogue (k2 WRITE 69->36MB).
// R17: HEAD-PAIR MERGE in k2 — each block computes 2 heads for its 128-s tile (grid 512):
//      B (xT) loaded ONCE for both heads and each chunk's barrier covers 40 MFMAs (was 20).
//      A-staging covers both heads (2x640 units/chunk, dbuf 40KB LDS). Softmax/PV/epilogue
//      per head sequentially, reusing Pt/T/acc3. launch_bounds(256,2) for VGPR headroom.
// R18/R19 (A-resident, zero-barrier score loop) tested and REVERTED: no gain with conflicts
//      controlled — k2's 53-58us plateau is a latency/issue property, not barriers/banks.
//      FINAL: best-measured configuration (117.86us).

typedef __attribute__((ext_vector_type(8))) short short8;
typedef __attribute__((ext_vector_type(4))) short short4v;
typedef __attribute__((ext_vector_type(4))) float f32x4;

#define DEV __device__ __forceinline__

DEV float bf2f(unsigned short u){ union{uint32_t i; float f;} x; x.i = ((uint32_t)u) << 16; return x.f; }
DEV unsigned short f2bf(float f){ __hip_bfloat16 h = __float2bfloat16(f); return *reinterpret_cast<unsigned short*>(&h); }
DEV short8 ld8(const unsigned short* p){ return *reinterpret_cast<const short8*>(p); }
DEV f32x4 ldf4(const float* p){ return *reinterpret_cast<const f32x4*>(p); }

#if defined(__has_builtin)
#if __has_builtin(__builtin_amdgcn_global_load_lds)
#define HAVE_ASYNC_LDS 1
#endif
#endif

// ---------------------------------------------------------------- fat kernel
// bx in {0,1}: K/V projection (uc = bx*8+by). bx == 2: Wq fp32 -> WqT[c][d] bf16.
// bx >= 3: x transpose tile (bx-3) -> tiled xTt.
__global__ __launch_bounds__(256) void k_fat(const float* __restrict__ x,
                                             unsigned short* __restrict__ xTt,
                                             const float* __restrict__ text,
                                             const float* __restrict__ Wk,
                                             const float* __restrict__ Wkb,
                                             const float* __restrict__ Wv,
                                             const float* __restrict__ Wvb,
                                             unsigned short* __restrict__ wsK,
                                             unsigned short* __restrict__ wsVt,
                                             const float* __restrict__ Wq,
                                             unsigned short* __restrict__ wsWqT,
                                             int b0, int s_base, int slen, int SB){
  __shared__ unsigned short U[16896];            // 64 x 264 (transpose) / KV arena / Wq tile
  const int tid = threadIdx.x;
  const int bx = blockIdx.x, by = blockIdx.y, bz = blockIdx.z;
  const int bg = b0 + bz;

  if (bx >= 3){
    // ---------------- transpose x[b][c0+r][s0..s0+256) fp32 -> xTt[bz][cc][sloc][r] bf16
    const int cc = by, c0 = cc * 64;
    const int tile = bx - 3;
    const int s0 = s_base + tile * 256;
    {
      const int r = tid >> 2, sub = tid & 3;     // 4 threads per c-row, 256B each
      const float* src = &x[((size_t)(bg * 512 + c0 + r)) * 4096 + s0 + sub * 64];
      f32x4 rv[16];
      #pragma unroll
      for (int i = 0; i < 16; ++i) rv[i] = ldf4(src + i * 4);   // all 16 loads in flight
      unsigned short* drow = &U[r * 264 + sub * 64];
      #pragma unroll
      for (int i = 0; i < 8; ++i){
        short8 v;
        #pragma unroll
        for (int j = 0; j < 4; ++j){ v[j] = (short)f2bf(rv[2*i][j]); v[j + 4] = (short)f2bf(rv[2*i+1][j]); }
        *reinterpret_cast<short8*>(drow + i * 8) = v;
      }
    }
    __syncthreads();
    {
      const int j = tid;                         // output s-row (local 0..255)
      unsigned short v[64];
      #pragma unroll
      for (int r = 0; r < 64; ++r) v[r] = U[r * 264 + j];   // column gather, 2-way banks (free)
      const int sloc = tile * 256 + j;
      unsigned short* dst = &xTt[(((size_t)bz * 8 + cc) * slen + sloc) * 64];
      #pragma unroll
      for (int g = 0; g < 8; ++g)
        *reinterpret_cast<short8*>(dst + g * 8) = *reinterpret_cast<short8*>(&v[g * 8]);
    }
  } else if (bx < 2){
    // ---------------- K/V projection: out[80l x 64u] = text[80x768] @ W[u]^T, BK=64
    // Register-prefetch dbuf: chunk k+1's 9 f32x4 loads issued before compute(k).
    unsigned short* At = U;                      // 80 x 72
    unsigned short* Bt = U + 5760;               // 64 x 72
    const int wave = tid >> 6, lane = tid & 63;
    const int m16 = lane & 15, quad = lane >> 4;
    const int uc = bx * 8 + by;
    const int u0 = uc * 64;
    const bool isK = (u0 < 512);
    const float* W  = isK ? Wk  : Wv;
    const float* Wb = isK ? Wkb : Wvb;
    const int c0 = u0 & 511;
    const int c  = c0 + wave * 16 + m16;         // this lane's output column

    int srow[9], se4[9]; bool sA[9], sval[9];
    #pragma unroll
    for (int it = 0; it < 9; ++it){
      int slot = tid + it * 256;
      if (slot < 1280){ sA[it] = true;  srow[it] = slot >> 4;          se4[it] = (slot & 15) * 4; sval[it] = (srow[it] < 77); }
      else            { sA[it] = false; srow[it] = (slot - 1280) >> 4; se4[it] = ((slot - 1280) & 15) * 4; sval[it] = true; }
    }
    f32x4 preg[9];
    auto issue = [&](int kc){
      const int e0 = kc * 64;
      #pragma unroll
      for (int it = 0; it < 9; ++it){
        if (sA[it])
          preg[it] = sval[it] ? ldf4(&text[((size_t)(bg * 77 + srow[it])) * 768 + e0 + se4[it]])
                              : (f32x4){0.f, 0.f, 0.f, 0.f};
        else
          preg[it] = ldf4(&W[((size_t)(c0 + srow[it])) * 768 + e0 + se4[it]]);
      }
    };
    auto write_lds = [&](){
      #pragma unroll
      for (int it = 0; it < 9; ++it){
        short4v o;
        #pragma unroll
        for (int j = 0; j < 4; ++j) o[j] = (short)f2bf(preg[it][j]);
        if (sA[it]) *reinterpret_cast<short4v*>(&At[srow[it] * 72 + se4[it]]) = o;
        else        *reinterpret_cast<short4v*>(&Bt[srow[it] * 72 + se4[it]]) = o;
      }
    };

    f32x4 acc[5];
    #pragma unroll
    for (int mt = 0; mt < 5; ++mt) acc[mt] = (f32x4){0.f, 0.f, 0.f, 0.f};
    issue(0);
    for (int kc = 0; kc < 12; ++kc){
      write_lds();                               // waits on prefetched loads
      __syncthreads();                           // LDS tile ready
      if (kc < 11) issue(kc + 1);                // next chunk's loads fly during compute
      #pragma unroll
      for (int kk = 0; kk < 64; kk += 32){
        short8 bf_ = *reinterpret_cast<const short8*>(&Bt[(wave * 16 + m16) * 72 + kk + quad * 8]);
        #pragma unroll
        for (int mt = 0; mt < 5; ++mt){
          short8 af_ = *reinterpret_cast<const short8*>(&At[(mt * 16 + m16) * 72 + kk + quad * 8]);
          acc[mt] = __builtin_amdgcn_mfma_f32_16x16x32_bf16(af_, bf_, acc[mt], 0, 0, 0);
        }
      }
      __syncthreads();                           // compute done before next overwrite
    }
    const float bias = Wb[c];
    if (isK){
      #pragma unroll
      for (int mt = 0; mt < 5; ++mt)
        #pragma unroll
        for (int r = 0; r < 4; ++r){
          int l = mt * 16 + quad * 4 + r;
          if (l < 77) wsK[((size_t)(bz * 77 + l)) * 512 + c] = f2bf(acc[mt][r] + bias);
        }
    } else {
      unsigned short* vr = &wsVt[((size_t)(bz * 512 + c)) * 96];
      #pragma unroll
      for (int mt = 0; mt < 5; ++mt){
        short4v pk;
        #pragma unroll
        for (int r = 0; r < 4; ++r) pk[r] = (short)f2bf(acc[mt][r] + bias);
        *reinterpret_cast<short4v*>(&vr[mt * 16 + quad * 4]) = pk;
      }
      short4v z = {};
      *reinterpret_cast<short4v*>(&vr[80 + quad * 4]) = z;   // zero l=80..95
    }
  } else {
    // ---------------- Wq[512 d][512 c] fp32 -> wsWqT[c][d] bf16 (64 tiles of 64x64, LDS transpose)
    unsigned short* t = U;                       // 64x72
    const int nb = 8 * SB;
    const int p  = by + bz * 8;
    for (int tile = p; tile < 64; tile += nb){
      const int ti = tile >> 3, tj = tile & 7;   // ti: c-tile, tj: d-tile
      {
        const int r = tid >> 2, sub = tid & 3;   // 4 threads per d-row, 16 c each
        const float* src = &Wq[((size_t)(tj * 64 + r)) * 512 + ti * 64 + sub * 16];
        f32x4 rv[4];
        #pragma unroll
        for (int i = 0; i < 4; ++i) rv[i] = ldf4(src + i * 4);
        unsigned short* drow = &t[r * 72 + sub * 16];
        #pragma unroll
        for (int i = 0; i < 2; ++i){
          short8 v;
          #pragma unroll
          for (int j = 0; j < 4; ++j){ v[j] = (short)f2bf(rv[2*i][j]); v[j + 4] = (short)f2bf(rv[2*i+1][j]); }
          *reinterpret_cast<short8*>(drow + i * 8) = v;
        }
      }
      __syncthreads();
      #pragma unroll
      for (int it = 0; it < 2; ++it){
        int slot = tid + it * 256;
        int j = slot >> 3, i8 = slot & 7;        // j: c-row out, i8: d-group
        short8 v;
        #pragma unroll
        for (int q = 0; q < 8; ++q)
          v[q] = (short)t[(i8 * 8 + q) * 72 + (j & 63)];
        *reinterpret_cast<short8*>(&wsWqT[((size_t)(ti * 64 + j)) * 512 + tj * 64 + i8 * 8]) = v;
      }
      __syncthreads();
    }
  }
}

// ---------------------------------------------------------------- k1b: KWq[l][c] = K_h[l][:] @ Wq_h[:][c],
// plus kb[l] = K_h[l][:]·Wqb_h. grid (cq=4, h=4, bz=SB). All operands bf16, direct from global (L2-hot).
__global__ __launch_bounds__(256) void k1b(const unsigned short* __restrict__ wsWqT,
                                           const unsigned short* __restrict__ wsK,
                                           const float* __restrict__ Wqb,
                                           unsigned short* __restrict__ wsKWq,
                                           float* __restrict__ kbias){
  const int tid = threadIdx.x;
  const int wave = tid >> 6, lane = tid & 63;
  const int m16 = lane & 15, quad = lane >> 4;
  const int cq = blockIdx.x, h = blockIdx.y, bz = blockIdx.z;
  const int cbase = cq * 128 + wave * 32;

  f32x4 acc[2][5];
  #pragma unroll
  for (int mt = 0; mt < 2; ++mt)
    #pragma unroll
    for (int nt = 0; nt < 5; ++nt) acc[mt][nt] = (f32x4){0.f, 0.f, 0.f, 0.f};

  #pragma unroll
  for (int ks = 0; ks < 4; ++ks){
    short8 aw[2];
    #pragma unroll
    for (int mt = 0; mt < 2; ++mt)
      aw[mt] = ld8(&wsWqT[(size_t)(cbase + mt * 16 + m16) * 512 + h * 128 + ks * 32 + quad * 8]);
    #pragma unroll
    for (int nt = 0; nt < 5; ++nt){
      int l = nt * 16 + m16;
      short8 bk = {};
      if (l < 77) bk = ld8(&wsK[((size_t)(bz * 77 + l)) * 512 + h * 128 + ks * 32 + quad * 8]);
      #pragma unroll
      for (int mt = 0; mt < 2; ++mt)
        acc[mt][nt] = __builtin_amdgcn_mfma_f32_16x16x32_bf16(aw[mt], bk, acc[mt][nt], 0, 0, 0);
    }
  }
  #pragma unroll
  for (int mt = 0; mt < 2; ++mt)
    #pragma unroll
    for (int nt = 0; nt < 5; ++nt){
      int l = nt * 16 + m16;
      short4v pk;
      #pragma unroll
      for (int r = 0; r < 4; ++r) pk[r] = (short)f2bf(acc[mt][nt][r]);
      *reinterpret_cast<short4v*>(&wsKWq[((size_t)((bz * 4 + h) * 80 + l)) * 512 + cbase + mt * 16 + quad * 4]) = pk;
    }
  if (cq == 0 && tid < 80){
    int l = tid;
    float kb = 0.f;
    if (l < 77){
      #pragma unroll
      for (int d = 0; d < 128; d += 8){
        short8 kv = ld8(&wsK[((size_t)(bz * 77 + l)) * 512 + h * 128 + d]);
        f32x4 wa = ldf4(&Wqb[h * 128 + d]);
        f32x4 wb = ldf4(&Wqb[h * 128 + d + 4]);
        #pragma unroll
        for (int j = 0; j < 4; ++j){
          kb += bf2f((unsigned short)kv[j]) * wa[j];
          kb += bf2f((unsigned short)kv[j + 4]) * wb[j];
        }
      }
    }
    kbias[(bz * 4 + h) * 80 + l] = kb;
  }
}

// ---------------------------------------------------------------- k2: scores + softmax + PV + GN partials
// HEAD-PAIR blocks: grid (bz, hp, st) = (SB, 2, slen/128); XCD = bz (R13). xT TILED [bz][cc][s][64].
// Per chunk: stage A for heads {2hp, 2hp+1} (2x640 units, 40KB dbuf), loadB ONCE, 40 MFMAs.
// Then per head: softmax -> Pt -> PV -> GN partials -> epilogue (bf16 transpose to outTmp).
__global__ __launch_bounds__(256, 2) void k2_attn(const unsigned short* __restrict__ xTt,
                                                  const unsigned short* __restrict__ wsKWq,
                                                  const unsigned short* __restrict__ wsVt,
                                                  const int* __restrict__ amask,
                                                  const float* __restrict__ kbias,
                                                  float* __restrict__ out,
                                                  unsigned short* __restrict__ outTmp,
                                                  float* __restrict__ gnacc,
                                                  int b0, int s_base, int slen, int useTmp){
  __shared__ unsigned short arena[20480];        // A dbuf 2x10240; Pt[128][104] & T[32][132] alias
  __shared__ float maskf[2][96];
  unsigned short* Pt = arena;                    // [128][104]

  const int tid = threadIdx.x;
  const int wave = tid >> 6, lane = tid & 63;
  const int m16 = lane & 15, quad = lane >> 4;
  const int bz = blockIdx.x, hp = blockIdx.y, st = blockIdx.z;   // XCD = bz
  const int bg = b0 + bz;
  const int s_glob = s_base + st * 128;
  const int R0 = (wave >> 1) * 64, C0 = (wave & 1) * 64;   // PV decomposition
  const int sw0 = wave * 32;                               // phase-A s-range of this wave
  const float scale = 0.08838834764831845f;                // 1/sqrt(128)

  if ((tid & 127) < 96){
    int hh = tid >> 7, l = tid & 127;
    int h = hp * 2 + hh;
    float mbv = -30000.f;
    if (l < 77 && amask[bg * 77 + l] != 0) mbv = kbias[(bz * 4 + h) * 80 + l] * scale;
    maskf[hh][l] = mbv;                                    // Q-bias folded into mask
  }

  const unsigned short* Ab[2];
  #pragma unroll
  for (int hh = 0; hh < 2; ++hh)
    Ab[hh] = wsKWq + (size_t)((bz * 4 + hp * 2 + hh) * 80) * 512;
  const unsigned short* Bb = xTt + (size_t)(bz * 8) * slen * 64;   // tiled batch base
  const int srow0 = st * 128 + sw0;                                // wave's s-row base

  f32x4 acc2[2][5][2];
  #pragma unroll
  for (int hh = 0; hh < 2; ++hh)
    #pragma unroll
    for (int mt = 0; mt < 5; ++mt){
      acc2[hh][mt][0] = (f32x4){0.f,0.f,0.f,0.f};
      acc2[hh][mt][1] = (f32x4){0.f,0.f,0.f,0.f};
    }

  // ---- A staging: 1280 units of 16B per chunk (head = u>=640; row l = uu>>3,
  // src pos pre-swizzled by l&7, linear LDS dest) so ds_read_b128 is 2-way (free).
  auto stageA = [&](int kc, int buf){
    const int sbase = buf * 10240;               // shorts
    #pragma unroll
    for (int it = 0; it < 5; ++it){
      const int ubase = it * 256 + wave * 64;
      const int u = ubase + lane;
      const int hh = (u >= 640) ? 1 : 0;
      const int uu = u - hh * 640;
      int l = uu >> 3, pos = (uu & 7) ^ (l & 7);
      const unsigned short* src = Ab[hh] + (size_t)l * 512 + kc * 64 + pos * 8;
#ifdef HAVE_ASYNC_LDS
      __builtin_amdgcn_global_load_lds((const __attribute__((address_space(1))) void*)src,
                                       (__attribute__((address_space(3))) void*)&arena[sbase + ubase * 8],
                                       16, 0, 0);
#else
      *reinterpret_cast<short8*>(&arena[sbase + u * 8]) = ld8(src);
#endif
    }
  };

  // ---- B fragments: per-wave-private rows srow0..+31, tiled layout, register dbuf; shared by both heads.
  short8 Breg[2][4];                             // [buf][nt*2+kk]
  auto loadB = [&](int kc, int buf){
    const unsigned short* Bc = Bb + ((size_t)kc * slen + srow0) * 64;
    #pragma unroll
    for (int nt = 0; nt < 2; ++nt)
      #pragma unroll
      for (int kk = 0; kk < 2; ++kk)
        Breg[buf][nt * 2 + kk] = ld8(&Bc[(size_t)(nt * 16 + m16) * 64 + kk * 32 + quad * 8]);
  };

  auto compute = [&](int buf){
    const int ab = buf * 10240;
    #pragma unroll
    for (int kk = 0; kk < 2; ++kk){
      #pragma unroll
      for (int hh = 0; hh < 2; ++hh){
        short8 af[5];
        #pragma unroll
        for (int mt = 0; mt < 5; ++mt){
          int l = mt * 16 + m16;
          int p = (kk * 4 + quad) ^ (l & 7);
          af[mt] = *reinterpret_cast<const short8*>(&arena[ab + hh * 5120 + l * 64 + p * 8]);
        }
        #pragma unroll
        for (int mt = 0; mt < 5; ++mt)
          #pragma unroll
          for (int nt = 0; nt < 2; ++nt)
            acc2[hh][mt][nt] = __builtin_amdgcn_mfma_f32_16x16x32_bf16(af[mt], Breg[buf][nt * 2 + kk], acc2[hh][mt][nt], 0, 0, 0);
      }
    }
  };

  stageA(0, 0);
  loadB(0, 0);
  __syncthreads();
  #pragma unroll
  for (int kc = 0; kc < 8; ++kc){
    if (kc < 7){ stageA(kc + 1, (kc + 1) & 1); loadB(kc + 1, (kc + 1) & 1); }
    compute(kc & 1);
    __syncthreads();                             // drains prefetch (overlapped with compute)
  }

  // ---- per head: softmax -> Pt -> PV -> GN partials -> epilogue
  #pragma unroll
  for (int hh = 0; hh < 2; ++hh){
    const int h = hp * 2 + hh;
    const unsigned short* Vb = wsVt + (size_t)(bz * 512 + h * 128) * 96;
    short8 av0[4];
    #pragma unroll
    for (int mt = 0; mt < 4; ++mt)
      av0[mt] = ld8(&Vb[(size_t)(R0 + mt * 16 + m16) * 96 + quad * 8]);

    // softmax over l (per s-column), Pt -> arena [s][l] stride 104
    {
      float mb[5][4];
      #pragma unroll
      for (int mt = 0; mt < 5; ++mt)
        #pragma unroll
        for (int r = 0; r < 4; ++r) mb[mt][r] = maskf[hh][mt * 16 + quad * 4 + r];
      #pragma unroll
      for (int nt = 0; nt < 2; ++nt){
        float sv[5][4]; float mx = -3e38f;
        #pragma unroll
        for (int mt = 0; mt < 5; ++mt)
          #pragma unroll
          for (int r = 0; r < 4; ++r){
            float v = acc2[hh][mt][nt][r] * scale + mb[mt][r];
            sv[mt][r] = v; mx = fmaxf(mx, v);
          }
        mx = fmaxf(mx, __shfl_xor(mx, 16)); mx = fmaxf(mx, __shfl_xor(mx, 32));
        float sum = 0.f;
        #pragma unroll
        for (int mt = 0; mt < 5; ++mt)
          #pragma unroll
          for (int r = 0; r < 4; ++r){ float e = __expf(sv[mt][r] - mx); sv[mt][r] = e; sum += e; }
        sum += __shfl_xor(sum, 16); sum += __shfl_xor(sum, 32);
        float inv = 1.0f / sum;
        int sl = sw0 + nt * 16 + m16;
        #pragma unroll
        for (int mt = 0; mt < 5; ++mt){
          short4v pk;
          #pragma unroll
          for (int r = 0; r < 4; ++r) pk[r] = (short)f2bf(sv[mt][r] * inv);
          *reinterpret_cast<short4v*>(&Pt[sl * 104 + mt * 16 + quad * 4]) = pk;
        }
        short4v z = {};
        *reinterpret_cast<short4v*>(&Pt[sl * 104 + 80 + quad * 4]) = z;  // zero l=80..95
      }
    }
    __syncthreads();                             // Pt ready for cross-wave reads

    // PV: Ot = Vt[128x96] @ Pt[96 x 128s]
    f32x4 acc3[4][4];
    #pragma unroll
    for (int mt = 0; mt < 4; ++mt)
      #pragma unroll
      for (int nt = 0; nt < 4; ++nt) acc3[mt][nt] = (f32x4){0.f, 0.f, 0.f, 0.f};
    #pragma unroll
    for (int ks = 0; ks < 3; ++ks){
      short8 av[4], bp[4];
      #pragma unroll
      for (int mt = 0; mt < 4; ++mt)
        av[mt] = (ks == 0) ? av0[mt]
                           : ld8(&Vb[(size_t)(R0 + mt * 16 + m16) * 96 + ks * 32 + quad * 8]);
      #pragma unroll
      for (int nt = 0; nt < 4; ++nt)
        bp[nt] = *reinterpret_cast<const short8*>(&Pt[(C0 + nt * 16 + m16) * 104 + ks * 32 + quad * 8]);
      #pragma unroll
      for (int mt = 0; mt < 4; ++mt)
        #pragma unroll
        for (int nt = 0; nt < 4; ++nt)
          acc3[mt][nt] = __builtin_amdgcn_mfma_f32_16x16x32_bf16(av[mt], bp[nt], acc3[mt][nt], 0, 0, 0);
    }

    // GN partials from fp32 accumulators
    float sum = 0.f, ssq = 0.f;
    #pragma unroll
    for (int mt = 0; mt < 4; ++mt)
      #pragma unroll
      for (int nt = 0; nt < 4; ++nt)
        #pragma unroll
        for (int r = 0; r < 4; ++r){
          float v = acc3[mt][nt][r];
          sum += v; ssq += v * v;
        }
    #pragma unroll
    for (int off = 1; off < 64; off <<= 1){ sum += __shfl_xor(sum, off); ssq += __shfl_xor(ssq, off); }
    if (lane == 0){
      int g = h * 2 + (R0 >> 6);
      atomicAdd(&gnacc[(bg * 8 + g) * 2],     sum);
      atomicAdd(&gnacc[(bg * 8 + g) * 2 + 1], ssq);
    }

    if (useTmp){
      // epilogue A: LDS transpose -> BF16 256B-contiguous rows outTmp[c][s_glob..+127]
      __syncthreads();                            // all Pt reads done; arena reused as T
      float* T = reinterpret_cast<float*>(arena); // [32][132]
      const int TS = 132;
      #pragma unroll
      for (int p = 0; p < 4; ++p){
        if ((R0 >> 6) == (p >> 1)){
          #pragma unroll
          for (int mt2 = 0; mt2 < 2; ++mt2){
            int mt = (p & 1) * 2 + mt2;
            #pragma unroll
            for (int nt = 0; nt < 4; ++nt)
              #pragma unroll
              for (int r = 0; r < 4; ++r)
                T[(mt2 * 16 + quad * 4 + r) * TS + C0 + nt * 16 + m16] = acc3[mt][nt][r];
          }
        }
        __syncthreads();
        #pragma unroll
        for (int it = 0; it < 4; ++it){
          int row = wave * 8 + it * 2 + (lane >> 5);  // 0..31
          int c = h * 128 + p * 32 + row;
          int sc = (lane & 31) * 4;
          f32x4 v = *reinterpret_cast<const f32x4*>(&T[row * TS + sc]);
          short4v o;
          #pragma unroll
          for (int j = 0; j < 4; ++j) o[j] = (short)f2bf(v[j]);
          *reinterpret_cast<short4v*>(&outTmp[(size_t)(bg * 512 + c) * 4096 + s_glob + sc]) = o;
        }
        __syncthreads();
      }
    } else {
      // epilogue B (fallback): scattered fp32 stores to out
      #pragma unroll
      for (int mt = 0; mt < 4; ++mt)
        #pragma unroll
        for (int nt = 0; nt < 4; ++nt){
          int sidx = s_glob + C0 + nt * 16 + m16;
          #pragma unroll
          for (int r = 0; r < 4; ++r){
            int d = h * 128 + R0 + mt * 16 + quad * 4 + r;
            out[(size_t)(bg * 512 + d) * 4096 + sidx] = acc3[mt][nt][r];
          }
        }
      __syncthreads();                            // Pt reads done before next head's overwrite
    }
  }
}

// ---------------------------------------------------------------- k3a: GN apply from bf16 tmp -> fp32 out
__global__ __launch_bounds__(256) void k3_gn_b(const unsigned short* __restrict__ tmp,
                                               float* __restrict__ out,
                                               const float* __restrict__ gnacc,
                                               const float* __restrict__ gns,
                                               const float* __restrict__ gnb){
  const int bx = blockIdx.x;                 // bx = b*512 + c
  const int b = bx >> 9, c = bx & 511;
  const int g = c >> 6;
  const float s  = gnacc[(b * 8 + g) * 2];
  const float ss = gnacc[(b * 8 + g) * 2 + 1];
  const float invN = 1.f / 262144.f;
  const float mean = s * invN;
  const float var  = ss * invN - mean * mean;
  const float rstd = rsqrtf(fmaxf(var, 0.f) + 1e-5f);
  const float a  = rstd * gns[c];
  const float bb = gnb[c] - mean * a;
  const size_t base = (size_t)bx * 4096;
  const unsigned short* src = &tmp[base + threadIdx.x * 16];
  float* dst = &out[base + threadIdx.x * 16];
  short8 v0 = ld8(src), v1 = ld8(src + 8);
  #pragma unroll
  for (int k = 0; k < 2; ++k){
    short8 v = k ? v1 : v0;
    f32x4 o0, o1;
    #pragma unroll
    for (int j = 0; j < 4; ++j){
      o0[j] = bf2f((unsigned short)v[j])     * a + bb;
      o1[j] = bf2f((unsigned short)v[j + 4]) * a + bb;
    }
    *reinterpret_cast<f32x4*>(dst + k * 8)     = o0;
    *reinterpret_cast<f32x4*>(dst + k * 8 + 4) = o1;
  }
}

// ---------------------------------------------------------------- k3b: GN apply in-place fp32 (fallback)
__global__ __launch_bounds__(256) void k3_gn(float* __restrict__ out,
                                             const float* __restrict__ gnacc,
                                             const float* __restrict__ gns,
                                             const float* __restrict__ gnb){
  const int bx = blockIdx.x;                 // bx = b*512 + c
  const int b = bx >> 9, c = bx & 511;
  const int g = c >> 6;
  const float s  = gnacc[(b * 8 + g) * 2];
  const float ss = gnacc[(b * 8 + g) * 2 + 1];
  const float invN = 1.f / 262144.f;
  const float mean = s * invN;
  const float var  = ss * invN - mean * mean;
  const float rstd = rsqrtf(fmaxf(var, 0.f) + 1e-5f);
  const float a  = rstd * gns[c];
  const float bb = gnb[c] - mean * a;
  const size_t base = (size_t)bx * 4096;
  #pragma unroll
  for (int p = 0; p < 4; ++p){
    size_t off = base + p * 1024 + threadIdx.x * 4;
    f32x4 v = ldf4(&out[off]);
    f32x4 o;
    #pragma unroll
    for (int j = 0; j < 4; ++j) o[j] = v[j] * a + bb;
    *reinterpret_cast<f32x4*>(&out[off]) = o;
  }
}

// ---------------------------------------------------------------- launch
extern "C" void kernel_launch(void* const* d_in, const int* in_sizes, int n_in,
                              void* d_out, int out_size, void* d_ws, size_t ws_size,
                              hipStream_t stream){
  (void)in_sizes; (void)n_in; (void)out_size;
  const float* x    = (const float*)d_in[0];
  const float* text = (const float*)d_in[1];
  const int*   am   = (const int*)d_in[2];
  const float* Wq   = (const float*)d_in[3];
  const float* Wqb  = (const float*)d_in[4];
  const float* Wk   = (const float*)d_in[5];
  const float* Wkb  = (const float*)d_in[6];
  const float* Wv   = (const float*)d_in[7];
  const float* Wvb  = (const float*)d_in[8];
  const float* gns  = (const float*)d_in[9];
  const float* gnb  = (const float*)d_in[10];
  float* out = (float*)d_out;

  // ws: gnacc 512 + wsWqT 512KB + SB*(wsK + wsVt + wsKWq + kbias) + SB*SLEN*1024 (xTt) [+ 32MB outTmp]
  auto need = [](int SB, int SLEN) -> size_t {
    return 512ull + 524288ull + (size_t)SB * 506112ull + (size_t)SB * SLEN * 1024ull;
  };
  int SB = 8, SLEN = 4096;
  if      (ws_size >= need(8, 4096)) { SB = 8; SLEN = 4096; }
  else if (ws_size >= need(4, 4096)) { SB = 4; SLEN = 4096; }
  else if (ws_size >= need(2, 4096)) { SB = 2; SLEN = 4096; }
  else if (ws_size >= need(1, 4096)) { SB = 1; SLEN = 4096; }
  else if (ws_size >= need(1, 1024)) { SB = 1; SLEN = 1024; }
  else                               { SB = 1; SLEN = 256;  }

  const size_t tmpBytes = 8ull * 512 * 4096 * 2;   // 32 MB bf16 intermediate
  const int useTmp = (SB == 8 && SLEN == 4096 && ws_size >= need(8, 4096) + tmpBytes) ? 1 : 0;

  uint8_t* ws = (uint8_t*)d_ws;
  float*          gnacc = (float*)ws;
  unsigned short* wsWqT = (unsigned short*)(ws + 512);                  // [512 c][512 d] bf16
  unsigned short* wsK   = wsWqT + 512 * 512;                            // [SB][77][512]
  unsigned short* wsVt  = wsK  + (size_t)SB * 77 * 512;                 // [SB][512][96]
  unsigned short* wsKWq = wsVt + (size_t)SB * 512 * 96;                 // [SB*4][80][512]
  float*          kbias = (float*)(wsKWq + (size_t)SB * 4 * 80 * 512);  // [SB*4][80]
  unsigned short* xTt   = (unsigned short*)(kbias + (size_t)SB * 4 * 80); // [SB][8cc][SLEN][64]
  unsigned short* outTmp = xTt + (size_t)SB * 8 * SLEN * 64;            // [8][512][4096] bf16

  hipMemsetAsync(gnacc, 0, 128 * sizeof(float), stream);
  for (int b0 = 0; b0 < 8; b0 += SB){
    for (int s_base = 0; s_base < 4096; s_base += SLEN){
      const int NT = SLEN >> 8;
      k_fat<<<dim3(NT + 3, 8, SB), 256, 0, stream>>>(x, xTt, text, Wk, Wkb, Wv, Wvb,
                                                     wsK, wsVt, Wq, wsWqT, b0, s_base, SLEN, SB);
      if (s_base == 0)
        k1b<<<dim3(4, 4, SB), 256, 0, stream>>>(wsWqT, wsK, Wqb, wsKWq, kbias);
      // XCD-aware grid (bz fastest, head-pair, st)
      k2_attn<<<dim3(SB, 2, SLEN / 128), 256, 0, stream>>>(xTt, wsKWq, wsVt, am, kbias,
                                                           out, outTmp, gnacc,
                                                           b0, s_base, SLEN, useTmp);
    }
  }
  if (useTmp)
    k3_gn_b<<<4096, 256, 0, stream>>>(outTmp, out, gnacc, gns, gnb);
  else
    k3_gn<<<4096, 256, 0, stream>>>(out, gnacc, gns, gnb);
}